// Round 21
// baseline (78.757 us; speedup 1.0000x reference)
//
#include <hip/hip_runtime.h>

// SSIM loss: predict/gt (32,1,512,512) f32, 11-tap separable gaussian (sigma=1.5),
// VALID padding -> 502x502 per image, loss = 1 - mean(ssim_map).
//
// Round 21: r20 (26.4us) + last-block final reduction (kills the 2nd kernel
// dispatch). Blocks store partials, threadfence, ticket-atomic; the last
// ticket holder sums 2560 partials and writes the loss. Counter zeroed by a
// 4B hipMemsetAsync each launch (graph-capturable, replay-deterministic).

typedef _Float16 f16;
typedef __attribute__((ext_vector_type(4))) _Float16 f16x4;
typedef __attribute__((ext_vector_type(8))) _Float16 f16x8;
typedef __attribute__((ext_vector_type(4))) float f32x4;

constexpr int WIN = 11;
constexpr int H = 512, W = 512, NIMG = 32;
constexpr int OH = H - WIN + 1, OW = W - WIN + 1;  // 502
constexpr int OR_ = 32;      // output rows per block (2 tiles of 16)
constexpr int OC = 112;      // output cols per block (7 groups of 16)
constexpr int SC = 128;      // staged cols (8 groups of 16)
constexpr int KP = 52;       // SB k-pitch in f16 (104B row; clean reads)
constexpr int NSTRIP = 16;   // ceil(502/32)
constexpr int NCB = 5;       // ceil(502/112)
constexpr int NBLK = NIMG * NSTRIP * NCB;  // 2560 (divisible by 8)
constexpr int CPX = NBLK / 8;              // 320 blocks per XCD
constexpr float C1 = 0.009801f;   // (0.01*9.9)^2
constexpr float C2 = 0.088209f;   // (0.03*9.9)^2
constexpr double TOTAL = (double)NIMG * (double)OH * (double)OW;

__device__ constexpr float WGT[WIN] = {
    0.0010285f, 0.0075988f, 0.0360008f, 0.1093607f, 0.2130054f,
    0.2660118f,
    0.2130054f, 0.1093607f, 0.0360008f, 0.0075988f, 0.0010285f};

__global__ __launch_bounds__(256, 4) void ssim_mfma_kernel(const float* __restrict__ P,
                                                           const float* __restrict__ G,
                                                           float* __restrict__ blocksum,
                                                           unsigned* __restrict__ counter,
                                                           float* __restrict__ out) {
    __shared__ f16 SB[2][SC][KP];    // staged p,g col-major in k (26624 B)
    __shared__ float wsum[4];
    __shared__ unsigned ticket;

    const int tid = threadIdx.x;
    const int lane = tid & 63;
    const int wid = tid >> 6;
    const int r = lane & 15;         // A row / B col / D col
    const int q = lane >> 4;         // k-group; D rows 4q..4q+3

    // bijective XCD swizzle: XCD x gets contiguous orig-bid range [x*320, x*320+320)
    const int bid0 = blockIdx.x;
    const int bid = (bid0 & 7) * CPX + (bid0 >> 3);

    const int img = bid / (NSTRIP * NCB);
    const int rem = bid % (NSTRIP * NCB);
    const int strip = rem / NCB;
    const int cb = rem % NCB;
    const int R0 = strip * OR_;
    const int C0 = cb * OC;

    // banded weight fragment computed inline (once per thread; ~40 VALU)
    f16x8 wfrag;
#pragma unroll
    for (int e = 0; e < 8; ++e) {
        const int k = (e < 4) ? (4 * q + e) : (16 + 4 * q + (e - 4));
        const int d = k - r;
        wfrag[e] = (d >= 0 && d <= 10) ? (f16)WGT[d] : (f16)0.f;
    }

    const float* p = P + (size_t)img * H * W;
    const float* g = G + (size_t)img * H * W;

    // ---- stage rows R0..R0+47 (clamped; clamp only feeds masked outputs),
    // float4 loads + register 4x4 transpose. 12 quads x 2 arr x 32 cg4 = 768 tasks.
#pragma unroll
    for (int tt = 0; tt < 3; ++tt) {
        const int t = tid + 256 * tt;
        const int cg4 = t & 31;
        const int arr = (t >> 5) & 1;
        const int quad = t >> 6;       // 0..11
        const float* src = arr ? g : p;
        const int gc4 = min(C0 + 4 * cg4, W - 4);
        f16 vals[4][4];
#pragma unroll
        for (int i = 0; i < 4; ++i) {
            const int row = min(R0 + 4 * quad + i, H - 1);
            const float4 v = *(const float4*)(src + (size_t)row * W + gc4);
            vals[i][0] = (f16)v.x; vals[i][1] = (f16)v.y;
            vals[i][2] = (f16)v.z; vals[i][3] = (f16)v.w;
        }
#pragma unroll
        for (int j = 0; j < 4; ++j) {
            const f16x4 c = {vals[0][j], vals[1][j], vals[2][j], vals[3][j]};
            *(f16x4*)&SB[arr][4 * cg4 + j][4 * quad] = c;
        }
    }
    __syncthreads();

    const f32x4 zero = {0.f, 0.f, 0.f, 0.f};
    float lsum = 0.f;

    // ---- two 16-row tiles share the staged buffer (tile T: k-offset 16T)
#pragma unroll
    for (int T = 0; T < 2; ++T) {
        const int koff = 16 * T;

        // vertical MFMA -> f16 fragments in registers (wave w: colgroups 2w..2w+2)
        f16x4 v16[3][5];
#pragma unroll
        for (int i = 0; i < 3; ++i) {
            const int cg = min(2 * wid + i, 7);
            const int col = cg * 16 + r;
            const f16* sb0 = &SB[0][col][koff];
            const f16* sb1 = &SB[1][col][koff];
            const f16x4 p0 = *(const f16x4*)(sb0 + 4 * q);
            const f16x4 p1 = *(const f16x4*)(sb0 + 16 + 4 * q);
            const f16x4 g0 = *(const f16x4*)(sb1 + 4 * q);
            const f16x4 g1 = *(const f16x4*)(sb1 + 16 + 4 * q);
            const f16x8 ap = __builtin_shufflevector(p0, p1, 0, 1, 2, 3, 4, 5, 6, 7);
            const f16x8 ag = __builtin_shufflevector(g0, g1, 0, 1, 2, 3, 4, 5, 6, 7);
            const f16x8 app = ap * ap;
            const f16x8 agg = ag * ag;
            const f16x8 apg = ap * ag;
            const f32x4 D0 = __builtin_amdgcn_mfma_f32_16x16x32_f16(ap,  wfrag, zero, 0, 0, 0);
            const f32x4 D1 = __builtin_amdgcn_mfma_f32_16x16x32_f16(ag,  wfrag, zero, 0, 0, 0);
            const f32x4 D2 = __builtin_amdgcn_mfma_f32_16x16x32_f16(app, wfrag, zero, 0, 0, 0);
            const f32x4 D3 = __builtin_amdgcn_mfma_f32_16x16x32_f16(agg, wfrag, zero, 0, 0, 0);
            const f32x4 D4 = __builtin_amdgcn_mfma_f32_16x16x32_f16(apg, wfrag, zero, 0, 0, 0);
#pragma unroll
            for (int m = 0; m < 4; ++m) {
                v16[i][0][m] = (f16)D0[m];
                v16[i][1][m] = (f16)D1[m];
                v16[i][2][m] = (f16)D2[m];
                v16[i][3][m] = (f16)D3[m];
                v16[i][4][m] = (f16)D4[m];
            }
        }

        // horizontal MFMA + SSIM: wave w covers outgroups 2w, 2w+1 (<7)
#pragma unroll
        for (int j = 0; j < 2; ++j) {
            const int og = 2 * wid + j;
            if (og < 7) {                  // wave-uniform
                f32x4 acc[5];
#pragma unroll
                for (int ch = 0; ch < 5; ++ch) {
                    const f16x8 afrag = __builtin_shufflevector(v16[j][ch], v16[j + 1][ch],
                                                                0, 1, 2, 3, 4, 5, 6, 7);
                    acc[ch] = __builtin_amdgcn_mfma_f32_16x16x32_f16(afrag, wfrag, zero, 0, 0, 0);
                }
                const int ocol = C0 + og * 16 + r;
#pragma unroll
                for (int m = 0; m < 4; ++m) {
                    const int orow = R0 + koff + 4 * q + m;
                    const bool ok = (orow < OH) && (ocol < OW);
                    const float m1 = acc[0][m], m2 = acc[1][m];
                    const float e11 = acc[2][m], e22 = acc[3][m], e12 = acc[4][m];
                    const float mu11 = m1 * m1, mu22 = m2 * m2, mu12 = m1 * m2;
                    const float s11 = e11 - mu11, s22 = e22 - mu22, s12 = e12 - mu12;
                    const float num = (2.f * mu12 + C1) * (2.f * s12 + C2);
                    const float den = (mu11 + mu22 + C1) * (s11 + s22 + C2);
                    lsum += ok ? __fdividef(num, den) : 0.f;
                }
            }
        }
    }

    // ---- block reduction -> partial store
#pragma unroll
    for (int off = 32; off > 0; off >>= 1)
        lsum += __shfl_down(lsum, off, 64);
    if (lane == 0) wsum[wid] = lsum;
    __syncthreads();
    if (tid == 0) {
        blocksum[bid0] = (wsum[0] + wsum[1]) + (wsum[2] + wsum[3]);
        __threadfence();                          // partials visible device-wide
        ticket = atomicAdd(counter, 1u);          // device-scope by default
    }
    __syncthreads();

    // ---- last block performs the final reduction
    if (ticket == (unsigned)(NBLK - 1)) {
        float s = 0.f;
        for (int i = tid; i < NBLK; i += 256)
            s += blocksum[i];
#pragma unroll
        for (int off = 32; off > 0; off >>= 1)
            s += __shfl_down(s, off, 64);
        if (lane == 0) wsum[wid] = s;
        __syncthreads();
        if (tid == 0) {
            const float total = (wsum[0] + wsum[1]) + (wsum[2] + wsum[3]);
            out[0] = 1.f - total * (float)(1.0 / TOTAL);
        }
    }
}

extern "C" void kernel_launch(void* const* d_in, const int* in_sizes, int n_in,
                              void* d_out, int out_size, void* d_ws, size_t ws_size,
                              hipStream_t stream) {
    const float* P = (const float*)d_in[0];   // predict
    const float* G = (const float*)d_in[1];   // gt
    float* out = (float*)d_out;
    unsigned* counter = (unsigned*)d_ws;                 // 4B ticket counter
    float* blocksum = (float*)((char*)d_ws + 4096);      // NBLK floats

    hipMemsetAsync(counter, 0, 4, stream);    // graph-capturable, per-replay reset
    ssim_mfma_kernel<<<NBLK, 256, 0, stream>>>(P, G, blocksum, counter, out);
}

// Round 22
// 26.087 us; speedup vs baseline: 3.0190x; 3.0190x over previous
//
#include <hip/hip_runtime.h>

// SSIM loss: predict/gt (32,1,512,512) f32, 11-tap separable gaussian (sigma=1.5),
// VALID padding -> 502x502 per image, loss = 1 - mean(ssim_map).
//
// Round 22: byte-identical revert to r20 (session best, 26.4us).
// r21's last-block reduction regressed 3x: per-block __threadfence() forces
// cross-XCD L2 writeback/drain (G16 coherence cost) -- two dispatches win.
// Structure: MFMA banded-weight conv (both passes), f16 V in registers,
// 32-row/112-col blocks, XCD swizzle, inline wfrag, (256,4).

typedef _Float16 f16;
typedef __attribute__((ext_vector_type(4))) _Float16 f16x4;
typedef __attribute__((ext_vector_type(8))) _Float16 f16x8;
typedef __attribute__((ext_vector_type(4))) float f32x4;

constexpr int WIN = 11;
constexpr int H = 512, W = 512, NIMG = 32;
constexpr int OH = H - WIN + 1, OW = W - WIN + 1;  // 502
constexpr int OR_ = 32;      // output rows per block (2 tiles of 16)
constexpr int OC = 112;      // output cols per block (7 groups of 16)
constexpr int SC = 128;      // staged cols (8 groups of 16)
constexpr int KP = 52;       // SB k-pitch in f16 (104B row; clean reads)
constexpr int NSTRIP = 16;   // ceil(502/32)
constexpr int NCB = 5;       // ceil(502/112)
constexpr int NBLK = NIMG * NSTRIP * NCB;  // 2560 (divisible by 8)
constexpr int CPX = NBLK / 8;              // 320 blocks per XCD
constexpr float C1 = 0.009801f;   // (0.01*9.9)^2
constexpr float C2 = 0.088209f;   // (0.03*9.9)^2
constexpr double TOTAL = (double)NIMG * (double)OH * (double)OW;

__device__ constexpr float WGT[WIN] = {
    0.0010285f, 0.0075988f, 0.0360008f, 0.1093607f, 0.2130054f,
    0.2660118f,
    0.2130054f, 0.1093607f, 0.0360008f, 0.0075988f, 0.0010285f};

__global__ __launch_bounds__(256, 4) void ssim_mfma_kernel(const float* __restrict__ P,
                                                           const float* __restrict__ G,
                                                           float* __restrict__ blocksum) {
    __shared__ f16 SB[2][SC][KP];    // staged p,g col-major in k (26624 B)
    __shared__ float wsum[4];

    const int tid = threadIdx.x;
    const int lane = tid & 63;
    const int wid = tid >> 6;
    const int r = lane & 15;         // A row / B col / D col
    const int q = lane >> 4;         // k-group; D rows 4q..4q+3

    // bijective XCD swizzle: XCD x gets contiguous orig-bid range [x*320, x*320+320)
    const int bid0 = blockIdx.x;
    const int bid = (bid0 & 7) * CPX + (bid0 >> 3);

    const int img = bid / (NSTRIP * NCB);
    const int rem = bid % (NSTRIP * NCB);
    const int strip = rem / NCB;
    const int cb = rem % NCB;
    const int R0 = strip * OR_;
    const int C0 = cb * OC;

    // banded weight fragment computed inline (once per thread; ~40 VALU)
    f16x8 wfrag;
#pragma unroll
    for (int e = 0; e < 8; ++e) {
        const int k = (e < 4) ? (4 * q + e) : (16 + 4 * q + (e - 4));
        const int d = k - r;
        wfrag[e] = (d >= 0 && d <= 10) ? (f16)WGT[d] : (f16)0.f;
    }

    const float* p = P + (size_t)img * H * W;
    const float* g = G + (size_t)img * H * W;

    // ---- stage rows R0..R0+47 (clamped; clamp only feeds masked outputs),
    // float4 loads + register 4x4 transpose. 12 quads x 2 arr x 32 cg4 = 768 tasks.
#pragma unroll
    for (int tt = 0; tt < 3; ++tt) {
        const int t = tid + 256 * tt;
        const int cg4 = t & 31;
        const int arr = (t >> 5) & 1;
        const int quad = t >> 6;       // 0..11
        const float* src = arr ? g : p;
        const int gc4 = min(C0 + 4 * cg4, W - 4);
        f16 vals[4][4];
#pragma unroll
        for (int i = 0; i < 4; ++i) {
            const int row = min(R0 + 4 * quad + i, H - 1);
            const float4 v = *(const float4*)(src + (size_t)row * W + gc4);
            vals[i][0] = (f16)v.x; vals[i][1] = (f16)v.y;
            vals[i][2] = (f16)v.z; vals[i][3] = (f16)v.w;
        }
#pragma unroll
        for (int j = 0; j < 4; ++j) {
            const f16x4 c = {vals[0][j], vals[1][j], vals[2][j], vals[3][j]};
            *(f16x4*)&SB[arr][4 * cg4 + j][4 * quad] = c;
        }
    }
    __syncthreads();

    const f32x4 zero = {0.f, 0.f, 0.f, 0.f};
    float lsum = 0.f;

    // ---- two 16-row tiles share the staged buffer (tile T: k-offset 16T)
#pragma unroll
    for (int T = 0; T < 2; ++T) {
        const int koff = 16 * T;

        // vertical MFMA -> f16 fragments in registers (wave w: colgroups 2w..2w+2)
        f16x4 v16[3][5];
#pragma unroll
        for (int i = 0; i < 3; ++i) {
            const int cg = min(2 * wid + i, 7);
            const int col = cg * 16 + r;
            const f16* sb0 = &SB[0][col][koff];
            const f16* sb1 = &SB[1][col][koff];
            const f16x4 p0 = *(const f16x4*)(sb0 + 4 * q);
            const f16x4 p1 = *(const f16x4*)(sb0 + 16 + 4 * q);
            const f16x4 g0 = *(const f16x4*)(sb1 + 4 * q);
            const f16x4 g1 = *(const f16x4*)(sb1 + 16 + 4 * q);
            const f16x8 ap = __builtin_shufflevector(p0, p1, 0, 1, 2, 3, 4, 5, 6, 7);
            const f16x8 ag = __builtin_shufflevector(g0, g1, 0, 1, 2, 3, 4, 5, 6, 7);
            const f16x8 app = ap * ap;
            const f16x8 agg = ag * ag;
            const f16x8 apg = ap * ag;
            const f32x4 D0 = __builtin_amdgcn_mfma_f32_16x16x32_f16(ap,  wfrag, zero, 0, 0, 0);
            const f32x4 D1 = __builtin_amdgcn_mfma_f32_16x16x32_f16(ag,  wfrag, zero, 0, 0, 0);
            const f32x4 D2 = __builtin_amdgcn_mfma_f32_16x16x32_f16(app, wfrag, zero, 0, 0, 0);
            const f32x4 D3 = __builtin_amdgcn_mfma_f32_16x16x32_f16(agg, wfrag, zero, 0, 0, 0);
            const f32x4 D4 = __builtin_amdgcn_mfma_f32_16x16x32_f16(apg, wfrag, zero, 0, 0, 0);
#pragma unroll
            for (int m = 0; m < 4; ++m) {
                v16[i][0][m] = (f16)D0[m];
                v16[i][1][m] = (f16)D1[m];
                v16[i][2][m] = (f16)D2[m];
                v16[i][3][m] = (f16)D3[m];
                v16[i][4][m] = (f16)D4[m];
            }
        }

        // horizontal MFMA + SSIM: wave w covers outgroups 2w, 2w+1 (<7)
#pragma unroll
        for (int j = 0; j < 2; ++j) {
            const int og = 2 * wid + j;
            if (og < 7) {                  // wave-uniform
                f32x4 acc[5];
#pragma unroll
                for (int ch = 0; ch < 5; ++ch) {
                    const f16x8 afrag = __builtin_shufflevector(v16[j][ch], v16[j + 1][ch],
                                                                0, 1, 2, 3, 4, 5, 6, 7);
                    acc[ch] = __builtin_amdgcn_mfma_f32_16x16x32_f16(afrag, wfrag, zero, 0, 0, 0);
                }
                const int ocol = C0 + og * 16 + r;
#pragma unroll
                for (int m = 0; m < 4; ++m) {
                    const int orow = R0 + koff + 4 * q + m;
                    const bool ok = (orow < OH) && (ocol < OW);
                    const float m1 = acc[0][m], m2 = acc[1][m];
                    const float e11 = acc[2][m], e22 = acc[3][m], e12 = acc[4][m];
                    const float mu11 = m1 * m1, mu22 = m2 * m2, mu12 = m1 * m2;
                    const float s11 = e11 - mu11, s22 = e22 - mu22, s12 = e12 - mu12;
                    const float num = (2.f * mu12 + C1) * (2.f * s12 + C2);
                    const float den = (mu11 + mu22 + C1) * (s11 + s22 + C2);
                    lsum += ok ? __fdividef(num, den) : 0.f;
                }
            }
        }
    }

    // ---- block reduction
#pragma unroll
    for (int off = 32; off > 0; off >>= 1)
        lsum += __shfl_down(lsum, off, 64);
    if (lane == 0) wsum[wid] = lsum;
    __syncthreads();
    if (tid == 0)
        blocksum[bid0] = (wsum[0] + wsum[1]) + (wsum[2] + wsum[3]);
}

// one-block reduction of 2560 block sums (640 float4, latency-overlapped)
__global__ __launch_bounds__(256) void reduce_kernel(const float4* __restrict__ bs4,
                                                     float* __restrict__ out) {
    const int tid = threadIdx.x;
    const float4 a0 = bs4[tid];
    const float4 a1 = bs4[tid + 256];
    float s = ((a0.x + a0.y) + (a0.z + a0.w))
            + ((a1.x + a1.y) + (a1.z + a1.w));
    if (tid < 128) {
        const float4 a2 = bs4[tid + 512];
        s += ((a2.x + a2.y) + (a2.z + a2.w));
    }
#pragma unroll
    for (int off = 32; off > 0; off >>= 1)
        s += __shfl_down(s, off, 64);
    __shared__ float wsum[4];
    const int wid = tid >> 6, lane = tid & 63;
    if (lane == 0) wsum[wid] = s;
    __syncthreads();
    if (tid == 0) {
        const float total = (wsum[0] + wsum[1]) + (wsum[2] + wsum[3]);
        out[0] = 1.f - total * (float)(1.0 / TOTAL);
    }
}

extern "C" void kernel_launch(void* const* d_in, const int* in_sizes, int n_in,
                              void* d_out, int out_size, void* d_ws, size_t ws_size,
                              hipStream_t stream) {
    const float* P = (const float*)d_in[0];   // predict
    const float* G = (const float*)d_in[1];   // gt
    float* out = (float*)d_out;
    float* blocksum = (float*)d_ws;           // NBLK floats

    ssim_mfma_kernel<<<NBLK, 256, 0, stream>>>(P, G, blocksum);
    reduce_kernel<<<1, 256, 0, stream>>>((const float4*)blocksum, out);
}